// Round 5
// baseline (279.353 us; speedup 1.0000x reference)
//
#include <hip/hip_runtime.h>
#include <hip/hip_bf16.h>
#include <hip/hip_cooperative_groups.h>

namespace cg = cooperative_groups;

#define NTYPES 64
#define DIM 64
#define GBLK 512         // cooperative grid: 512 blocks = 2/CU guaranteed resident
#define BLK 256
#define HB 64            // fallback histogram blocks

typedef short bf16x8 __attribute__((ext_vector_type(8)));
typedef float f32x4  __attribute__((ext_vector_type(4)));

static __device__ __forceinline__ short f2bf(float f) {
    __hip_bfloat16 h = __float2bfloat16(f);   // RNE
    return *reinterpret_cast<short*>(&h);
}

// ===================== fused cooperative kernel =====================
__global__ __launch_bounds__(BLK) void fused_k(const float* __restrict__ x,
                                               const int* __restrict__ types,
                                               const float* __restrict__ M,
                                               const float* __restrict__ bias,
                                               int n,
                                               int* __restrict__ part,
                                               int* __restrict__ start,
                                               int* __restrict__ cursor,
                                               int* __restrict__ tstart,
                                               int* __restrict__ perm,
                                               short* __restrict__ Mt,
                                               float* __restrict__ out) {
    cg::grid_group grid = cg::this_grid();
    int tid = threadIdx.x;
    int bid = blockIdx.x;

    __shared__ int lh[NTYPES];
    __shared__ int lbase[NTYPES];
    __shared__ __align__(16) float Msh[DIM * 68];   // 17408 B, stride 68 fl = 272 B (16B-mult)
    __shared__ int smt[NTYPES + 1];
    __shared__ int sms[NTYPES + 1];
    __shared__ int ps[4][NTYPES];

    // ---------- Phase A: histogram partials + Mt[t][o][k] transpose ----------
    if (tid < NTYPES) lh[tid] = 0;
    __syncthreads();
    for (int i = bid * BLK + tid; i < n; i += GBLK * BLK)
        atomicAdd(&lh[types[i]], 1);
    __syncthreads();
    if (tid < NTYPES) part[bid * NTYPES + tid] = lh[tid];

    if (bid < NTYPES) {               // block-uniform branch; barriers inside are safe
        int t = bid;
        const float4* Msrc = (const float4*)(M + ((size_t)t << 12));
        #pragma unroll
        for (int i = 0; i < 4; ++i) {
            int f = tid + BLK * i;    // 0..1023 float4s
            int k = f >> 4;
            int cs = f & 15;
            *(float4*)(Msh + k * 68 + cs * 4) = Msrc[f];
        }
        __syncthreads();
        int o = tid >> 2, ks = tid & 3;
        short vals[16];
        #pragma unroll
        for (int j = 0; j < 16; ++j)
            vals[j] = f2bf(Msh[(ks * 16 + j) * 68 + o]);
        short* dst = Mt + ((size_t)t << 12) + o * DIM + ks * 16;
        *(bf16x8*)(dst)     = *(const bf16x8*)(vals);
        *(bf16x8*)(dst + 8) = *(const bf16x8*)(vals + 8);
    }

    grid.sync();

    // ---------- Phase B: reduce partials + dual exclusive scans (block 0) ----------
    if (bid == 0) {
        int t = tid & 63, seg = tid >> 6;
        int s = 0;
        for (int i = 0; i < GBLK / 4; ++i)
            s += part[(seg * (GBLK / 4) + i) * NTYPES + t];   // coalesced 256B rows
        ps[seg][t] = s;
        __syncthreads();
        if (tid < 64) {
            int sum = ps[0][t] + ps[1][t] + ps[2][t] + ps[3][t];
            int inc = sum;
            #pragma unroll
            for (int d = 1; d < 64; d <<= 1) { int u = __shfl_up(inc, d); if (t >= d) inc += u; }
            start[t]  = inc - sum;
            cursor[t] = inc - sum;
            if (t == 63) start[64] = inc;
            int tl = (sum + 15) >> 4;                 // tiles for this type
            int inct = tl;
            #pragma unroll
            for (int d = 1; d < 64; d <<= 1) { int u = __shfl_up(inct, d); if (t >= d) inct += u; }
            tstart[t] = inct - tl;
            if (t == 63) tstart[64] = inct;
        }
    }

    grid.sync();

    // ---------- Phase C: block-aggregated scatter -> perm (type-sorted) ----------
    if (tid < NTYPES) lh[tid] = 0;
    __syncthreads();
    int gi = bid * BLK + tid;          // GBLK*BLK = 131072 >= n, one element each
    int myt = -1, myo = 0;
    if (gi < n) { myt = types[gi]; myo = atomicAdd(&lh[myt], 1); }
    __syncthreads();
    if (tid < NTYPES) lbase[tid] = lh[tid] ? atomicAdd(&cursor[tid], lh[tid]) : 0;
    __syncthreads();
    if (myt >= 0) perm[lbase[myt] + myo] = gi;

    grid.sync();

    // ---------- Phase D: flat-work-list MFMA grouped GEMM ----------
    if (tid < NTYPES + 1) { smt[tid] = tstart[tid]; sms[tid] = start[tid]; }
    __syncthreads();
    int T    = smt[NTYPES];
    int lane = tid & 63;
    int wv   = tid >> 6;
    int col  = lane & 15;     // atom within 16-atom tile
    int hi   = lane >> 4;     // k-group / 4-output sub-row

    for (int item = bid * 4 + wv; item < T; item += GBLK * 4) {
        // uniform binary search: largest t with smt[t] <= item
        int lo = 0, hh = NTYPES;
        while (hh - lo > 1) { int mid = (lo + hh) >> 1; if (smt[mid] <= item) lo = mid; else hh = mid; }
        int t = lo;
        int abase = sms[t] + ((item - smt[t]) << 4);
        int lim   = sms[t + 1];

        int aidx  = abase + col;
        bool valid = aidx < lim;
        if (!valid) aidx = lim - 1;    // clamped read; store guarded
        int g = perm[aidx];

        const float* xr = x + ((size_t)g << 6);
        float4 p0 = *(const float4*)(xr + hi * 8);
        float4 p1 = *(const float4*)(xr + hi * 8 + 4);
        float4 p2 = *(const float4*)(xr + 32 + hi * 8);
        float4 p3 = *(const float4*)(xr + 32 + hi * 8 + 4);
        bf16x8 b0, b1;
        b0[0] = f2bf(p0.x); b0[1] = f2bf(p0.y); b0[2] = f2bf(p0.z); b0[3] = f2bf(p0.w);
        b0[4] = f2bf(p1.x); b0[5] = f2bf(p1.y); b0[6] = f2bf(p1.z); b0[7] = f2bf(p1.w);
        b1[0] = f2bf(p2.x); b1[1] = f2bf(p2.y); b1[2] = f2bf(p2.z); b1[3] = f2bf(p2.w);
        b1[4] = f2bf(p3.x); b1[5] = f2bf(p3.y); b1[6] = f2bf(p3.z); b1[7] = f2bf(p3.w);

        f32x4 acc[4];
        const short* At = Mt + ((size_t)t << 12);
        #pragma unroll
        for (int ct = 0; ct < 4; ++ct) {
            const short* ar = At + (ct * 16 + col) * DIM + hi * 8;
            bf16x8 a0 = *(const bf16x8*)(ar);
            bf16x8 a1 = *(const bf16x8*)(ar + 32);
            acc[ct] = *(const f32x4*)(bias + t * DIM + ct * 16 + hi * 4);
            acc[ct] = __builtin_amdgcn_mfma_f32_16x16x32_bf16(a0, b0, acc[ct], 0, 0, 0);
            acc[ct] = __builtin_amdgcn_mfma_f32_16x16x32_bf16(a1, b1, acc[ct], 0, 0, 0);
        }

        if (valid) {
            float* orow = out + ((size_t)g << 6);
            #pragma unroll
            for (int ct = 0; ct < 4; ++ct)
                *(f32x4*)(orow + ct * 16 + hi * 4) = acc[ct];
        }
    }
}

// ===================== fallback (non-cooperative) path =====================
__global__ void hist_mtr_k(const int* __restrict__ types, int n, int* __restrict__ part,
                           const float* __restrict__ M, short* __restrict__ Mt) {
    __shared__ int lh[NTYPES];
    int tid = threadIdx.x;
    int t = blockIdx.x;
    if (tid < NTYPES) lh[tid] = 0;
    __syncthreads();
    for (int i = t * blockDim.x + tid; i < n; i += gridDim.x * blockDim.x)
        atomicAdd(&lh[types[i]], 1);
    {
        int o  = tid >> 2;
        int ks = tid & 3;
        const float* Ms = M + ((size_t)t << 12);
        short vals[16];
        #pragma unroll
        for (int j = 0; j < 16; ++j)
            vals[j] = f2bf(Ms[(ks * 16 + j) * DIM + o]);
        short* dst = Mt + ((size_t)t << 12) + o * DIM + ks * 16;
        *(bf16x8*)(dst)     = *(const bf16x8*)(vals);
        *(bf16x8*)(dst + 8) = *(const bf16x8*)(vals + 8);
    }
    __syncthreads();
    if (tid < NTYPES) part[t * NTYPES + tid] = lh[tid];
}

__global__ void scan_k(const int* __restrict__ part, int* __restrict__ start,
                       int* __restrict__ cursor) {
    __shared__ int ps[4][NTYPES];
    int tid = threadIdx.x;
    int t = tid & 63, seg = tid >> 6;
    int s = 0;
    #pragma unroll
    for (int i = 0; i < HB / 4; ++i)
        s += part[(seg * (HB / 4) + i) * NTYPES + t];
    ps[seg][t] = s;
    __syncthreads();
    if (tid < 64) {
        int sum = ps[0][t] + ps[1][t] + ps[2][t] + ps[3][t];
        int inc = sum;
        #pragma unroll
        for (int d = 1; d < 64; d <<= 1) { int u = __shfl_up(inc, d); if (t >= d) inc += u; }
        start[t] = inc - sum;
        cursor[t] = inc - sum;
        if (t == 63) start[NTYPES] = inc;
    }
}

__global__ void scatter_k(const int* __restrict__ types, int n, int* __restrict__ cursor,
                          int* __restrict__ perm) {
    __shared__ int lh[NTYPES];
    __shared__ int lbase[NTYPES];
    int tid = threadIdx.x;
    if (tid < NTYPES) lh[tid] = 0;
    __syncthreads();
    const int PER = 4;
    int base = blockIdx.x * blockDim.x * PER;
    int myt[PER], myo[PER];
    #pragma unroll
    for (int k = 0; k < PER; ++k) {
        int i = base + k * blockDim.x + tid;
        if (i < n) { myt[k] = types[i]; myo[k] = atomicAdd(&lh[myt[k]], 1); }
        else myt[k] = -1;
    }
    __syncthreads();
    if (tid < NTYPES) lbase[tid] = lh[tid] ? atomicAdd(&cursor[tid], lh[tid]) : 0;
    __syncthreads();
    #pragma unroll
    for (int k = 0; k < PER; ++k)
        if (myt[k] >= 0)
            perm[lbase[myt[k]] + myo[k]] = base + k * blockDim.x + tid;
}

__global__ __launch_bounds__(256) void main_k(const float* __restrict__ x,
                                              const short* __restrict__ Mt,
                                              const float* __restrict__ bias,
                                              const int* __restrict__ start,
                                              const int* __restrict__ perm,
                                              float* __restrict__ out) {
    int t = blockIdx.x;
    int s0 = start[t];
    int cnt = start[t + 1] - s0;
    if (cnt <= 0) return;
    int tid  = threadIdx.x;
    int lane = tid & 63;
    int wave = tid >> 6;
    int col  = lane & 15;
    int hi   = lane >> 4;
    const short* At = Mt + ((size_t)t << 12);
    int nt  = (cnt + 15) >> 4;
    int lim = s0 + cnt;
    for (int tau = blockIdx.y * 4 + wave; tau < nt; tau += gridDim.y * 4) {
        int abase = s0 + (tau << 4);
        int aidx  = abase + col;
        bool valid = aidx < lim;
        if (!valid) aidx = lim - 1;
        int g = perm[aidx];
        const float* xr = x + ((size_t)g << 6);
        float4 p0 = *(const float4*)(xr + hi * 8);
        float4 p1 = *(const float4*)(xr + hi * 8 + 4);
        float4 p2 = *(const float4*)(xr + 32 + hi * 8);
        float4 p3 = *(const float4*)(xr + 32 + hi * 8 + 4);
        bf16x8 b0, b1;
        b0[0] = f2bf(p0.x); b0[1] = f2bf(p0.y); b0[2] = f2bf(p0.z); b0[3] = f2bf(p0.w);
        b0[4] = f2bf(p1.x); b0[5] = f2bf(p1.y); b0[6] = f2bf(p1.z); b0[7] = f2bf(p1.w);
        b1[0] = f2bf(p2.x); b1[1] = f2bf(p2.y); b1[2] = f2bf(p2.z); b1[3] = f2bf(p2.w);
        b1[4] = f2bf(p3.x); b1[5] = f2bf(p3.y); b1[6] = f2bf(p3.z); b1[7] = f2bf(p3.w);
        f32x4 acc[4];
        #pragma unroll
        for (int ct = 0; ct < 4; ++ct) {
            const short* ar = At + (ct * 16 + col) * DIM + hi * 8;
            bf16x8 a0 = *(const bf16x8*)(ar);
            bf16x8 a1 = *(const bf16x8*)(ar + 32);
            acc[ct] = *(const f32x4*)(bias + t * DIM + ct * 16 + hi * 4);
            acc[ct] = __builtin_amdgcn_mfma_f32_16x16x32_bf16(a0, b0, acc[ct], 0, 0, 0);
            acc[ct] = __builtin_amdgcn_mfma_f32_16x16x32_bf16(a1, b1, acc[ct], 0, 0, 0);
        }
        if (valid) {
            float* orow = out + ((size_t)g << 6);
            #pragma unroll
            for (int ct = 0; ct < 4; ++ct)
                *(f32x4*)(orow + ct * 16 + hi * 4) = acc[ct];
        }
    }
}

extern "C" void kernel_launch(void* const* d_in, const int* in_sizes, int n_in,
                              void* d_out, int out_size, void* d_ws, size_t ws_size,
                              hipStream_t stream) {
    const float* x     = (const float*)d_in[0];
    const int*   types = (const int*)d_in[1];
    const float* M     = (const float*)d_in[2];
    const float* bias  = (const float*)d_in[3];
    float* out = (float*)d_out;
    int n = in_sizes[1];

    // ws (ints): part[512*64] | start[65] @+0 | cursor @+72 | tstart @+144 | perm @+256 | Mt
    int* part   = (int*)d_ws;
    int* hdr    = part + GBLK * NTYPES;
    int* start  = hdr;
    int* cursor = hdr + 72;
    int* tstart = hdr + 144;
    int* perm   = hdr + 256;
    short* Mt   = (short*)(perm + ((n + 7) & ~7));   // 16B-aligned

    void* args[12] = { (void*)&x, (void*)&types, (void*)&M, (void*)&bias, (void*)&n,
                       (void*)&part, (void*)&start, (void*)&cursor, (void*)&tstart,
                       (void*)&perm, (void*)&Mt, (void*)&out };
    hipError_t e = hipLaunchCooperativeKernel(reinterpret_cast<void*>(fused_k),
                                              dim3(GBLK), dim3(BLK), args, 0, stream);
    if (e != hipSuccess) {
        // fallback: 4-kernel non-cooperative path (same math, same ws layout)
        hist_mtr_k<<<HB, 256, 0, stream>>>(types, n, part, M, Mt);
        scan_k<<<1, 256, 0, stream>>>(part, start, cursor);
        scatter_k<<<(n + 1023) / 1024, 256, 0, stream>>>(types, n, cursor, perm);
        main_k<<<dim3(NTYPES, 26), 256, 0, stream>>>(x, Mt, bias, start, perm, out);
    }
}

// Round 6
// 95.495 us; speedup vs baseline: 2.9253x; 2.9253x over previous
//
#include <hip/hip_runtime.h>
#include <hip/hip_bf16.h>

#define NTYPES 64
#define DIM 64
#define CAP 4096          // per-type perm region capacity (max count ~1.7k, 2.4x margin)

typedef short bf16x8 __attribute__((ext_vector_type(8)));
typedef float f32x4  __attribute__((ext_vector_type(4)));

static __device__ __forceinline__ short f2bf(float f) {
    __hip_bfloat16 h = __float2bfloat16(f);   // RNE
    return *reinterpret_cast<short*>(&h);
}

// ---------------- K1: direct-claim scatter (grouped perm) + fused M transpose ------
// grid = 98 blocks x 256 thr, PER=4 atoms/thread. Blocks 0..63 also emit
// Mt[t][o][k] = bf16(M[t][k][o]). Counts end up in cursor[t] (zeroed by memset).
__global__ void scatter_mtr_k(const int* __restrict__ types, int n,
                              int* __restrict__ cursor, int* __restrict__ perm,
                              const float* __restrict__ M, short* __restrict__ Mt) {
    __shared__ int lh[NTYPES];
    __shared__ int lbase[NTYPES];
    int tid = threadIdx.x;
    int bid = blockIdx.x;
    if (tid < NTYPES) lh[tid] = 0;
    __syncthreads();

    const int PER = 4;
    int base = bid * blockDim.x * PER;
    int myt[PER], myo[PER];
    #pragma unroll
    for (int k = 0; k < PER; ++k) {
        int i = base + k * blockDim.x + tid;      // coalesced
        if (i < n) {
            myt[k] = types[i];
            myo[k] = atomicAdd(&lh[myt[k]], 1);
        } else myt[k] = -1;
    }
    __syncthreads();
    if (tid < NTYPES) lbase[tid] = lh[tid] ? atomicAdd(&cursor[tid], lh[tid]) : 0;
    __syncthreads();
    #pragma unroll
    for (int k = 0; k < PER; ++k)
        if (myt[k] >= 0)
            perm[myt[k] * CAP + lbase[myt[k]] + myo[k]] = base + k * blockDim.x + tid;

    // ---- fused transpose: block t builds Mt[t] (M is 1MB, L2-resident) ----
    if (bid < NTYPES) {
        int t  = bid;
        int o  = tid >> 2;          // 0..63
        int ks = tid & 3;           // 16-k segment
        const float* Ms = M + ((size_t)t << 12);
        short vals[16];
        #pragma unroll
        for (int j = 0; j < 16; ++j)
            vals[j] = f2bf(Ms[(ks * 16 + j) * DIM + o]);
        short* dst = Mt + ((size_t)t << 12) + o * DIM + ks * 16;
        *(bf16x8*)(dst)     = *(const bf16x8*)(vals);
        *(bf16x8*)(dst + 8) = *(const bf16x8*)(vals + 8);
    }
}

// ---------------- K2: MFMA grouped GEMM, reg-resident matrix ----------------
// grid = (64 types, 8 slots) x 256 thr = 2048 waves, ~3 tiles/wave.
// Wave-tile = 16 atoms x 64 outs. A = Mt (hoisted to 16 VGPR once per wave),
// B = x gather (bf16 cvt in-flight), D: lane = 4 consecutive outs of one atom.
__global__ __launch_bounds__(256) void main_k(const float* __restrict__ x,
                                              const short* __restrict__ Mt,
                                              const float* __restrict__ bias,
                                              const int* __restrict__ cursor,
                                              const int* __restrict__ perm,
                                              float* __restrict__ out) {
    int t = blockIdx.x;
    int cnt = cursor[t];
    if (cnt <= 0) return;

    int tid  = threadIdx.x;
    int lane = tid & 63;
    int wv   = tid >> 6;
    int col  = lane & 15;     // atom within tile
    int hi   = lane >> 4;     // k-group / 4-output sub-row

    // ---- hoist A fragments + bias (type-invariant) ----
    const short* At = Mt + ((size_t)t << 12);
    bf16x8 a0[4], a1[4];
    f32x4  bsv[4];
    #pragma unroll
    for (int ct = 0; ct < 4; ++ct) {
        const short* ar = At + (ct * 16 + col) * DIM + hi * 8;
        a0[ct] = *(const bf16x8*)(ar);
        a1[ct] = *(const bf16x8*)(ar + 32);
        bsv[ct] = *(const f32x4*)(bias + t * DIM + ct * 16 + hi * 4);
    }

    const int* pbase = perm + t * CAP;
    int nt = (cnt + 15) >> 4;

    for (int tau = blockIdx.y * 4 + wv; tau < nt; tau += gridDim.y * 4) {
        int a = (tau << 4) + col;
        bool valid = a < cnt;
        if (!valid) a = cnt - 1;          // clamped read; store guarded
        int g = pbase[a];

        const float* xr = x + ((size_t)g << 6);
        float4 p0 = *(const float4*)(xr + hi * 8);
        float4 p1 = *(const float4*)(xr + hi * 8 + 4);
        float4 p2 = *(const float4*)(xr + 32 + hi * 8);
        float4 p3 = *(const float4*)(xr + 32 + hi * 8 + 4);
        bf16x8 b0, b1;
        b0[0] = f2bf(p0.x); b0[1] = f2bf(p0.y); b0[2] = f2bf(p0.z); b0[3] = f2bf(p0.w);
        b0[4] = f2bf(p1.x); b0[5] = f2bf(p1.y); b0[6] = f2bf(p1.z); b0[7] = f2bf(p1.w);
        b1[0] = f2bf(p2.x); b1[1] = f2bf(p2.y); b1[2] = f2bf(p2.z); b1[3] = f2bf(p2.w);
        b1[4] = f2bf(p3.x); b1[5] = f2bf(p3.y); b1[6] = f2bf(p3.z); b1[7] = f2bf(p3.w);

        f32x4 acc[4];
        #pragma unroll
        for (int ct = 0; ct < 4; ++ct) {
            acc[ct] = bsv[ct];
            acc[ct] = __builtin_amdgcn_mfma_f32_16x16x32_bf16(a0[ct], b0, acc[ct], 0, 0, 0);
            acc[ct] = __builtin_amdgcn_mfma_f32_16x16x32_bf16(a1[ct], b1, acc[ct], 0, 0, 0);
        }

        if (valid) {
            float* orow = out + ((size_t)g << 6);
            #pragma unroll
            for (int ct = 0; ct < 4; ++ct)
                *(f32x4*)(orow + ct * 16 + hi * 4) = acc[ct];
        }
    }
}

extern "C" void kernel_launch(void* const* d_in, const int* in_sizes, int n_in,
                              void* d_out, int out_size, void* d_ws, size_t ws_size,
                              hipStream_t stream) {
    const float* x     = (const float*)d_in[0];
    const int*   types = (const int*)d_in[1];
    const float* M     = (const float*)d_in[2];
    const float* bias  = (const float*)d_in[3];
    float* out = (float*)d_out;
    int n = in_sizes[1];

    // ws (ints): cursor[64] | pad->256 | perm[64*CAP] | Mt (bf16, 512KB)
    int* cursor = (int*)d_ws;
    int* perm   = cursor + 256;                       // 1KB-aligned
    short* Mt   = (short*)(perm + NTYPES * CAP);      // 16B-aligned

    hipMemsetAsync(cursor, 0, NTYPES * sizeof(int), stream);
    scatter_mtr_k<<<(n + 1023) / 1024, 256, 0, stream>>>(types, n, cursor, perm, M, Mt);
    main_k<<<dim3(NTYPES, 8), 256, 0, stream>>>(x, Mt, bias, cursor, perm, out);
}